// Round 2
// baseline (337.438 us; speedup 1.0000x reference)
//
#include <hip/hip_runtime.h>

#define BB 8
#define TT 4096
#define FF 481
#define NF 96
#define FS 5

__global__ __launch_bounds__(256) void df_kernel(
    const float2* __restrict__ spec,   // (B,1,T,F) complex pairs
    const float2* __restrict__ coefs,  // (B,FS,T,NF) complex pairs
    float2* __restrict__ out)          // (B,1,T,F) complex pairs
{
    const int f = blockIdx.x * 256 + threadIdx.x;
    const int t = blockIdx.y;
    const int b = blockIdx.z;
    if (f >= FF) return;

    const long long sidx = ((long long)b * TT + t) * FF + f;

    if (f >= NF) {
        // passthrough: spec_hi
        out[sidx] = spec[sidx];
        return;
    }

    float acc_re = 0.f, acc_im = 0.f;
#pragma unroll
    for (int i = 0; i < FS; ++i) {
        const int ts = t + i - (FS - 1);
        if (ts < 0) continue;
        const float2 s = spec[((long long)b * TT + ts) * FF + f];
        const float2 c = coefs[(((long long)b * FS + i) * TT + t) * NF + f];
        acc_re = fmaf(s.x, c.x, acc_re);
        acc_re = fmaf(-s.y, c.y, acc_re);
        acc_im = fmaf(s.x, c.y, acc_im);
        acc_im = fmaf(s.y, c.x, acc_im);
    }

    float2 r; r.x = acc_re; r.y = acc_im;
    out[sidx] = r;
}

extern "C" void kernel_launch(void* const* d_in, const int* in_sizes, int n_in,
                              void* d_out, int out_size, void* d_ws, size_t ws_size,
                              hipStream_t stream) {
    const float2* spec  = (const float2*)d_in[0];
    const float2* coefs = (const float2*)d_in[1];
    float2* out = (float2*)d_out;

    dim3 grid((FF + 255) / 256, TT, BB);  // (2, 4096, 8)
    df_kernel<<<grid, dim3(256), 0, stream>>>(spec, coefs, out);
}

// Round 3
// 303.267 us; speedup vs baseline: 1.1127x; 1.1127x over previous
//
#include <hip/hip_runtime.h>

#define BB 8
#define TT 4096
#define FF 481
#define NF 96
#define FS 5

#define N_FILT (BB * TT * NF)          // 3,145,728 complex pairs
#define N_HI   (BB * TT * (FF - NF))   // 12,615,680 complex pairs
#define NBLK   4096
#define FB     1920                     // filter blocks; rest do the hi-copy

__global__ __launch_bounds__(256) void df_all(
    const float2* __restrict__ spec,   // (B,1,T,F) complex pairs
    const float2* __restrict__ coefs,  // (B,FS,T,NF) complex pairs
    float2* __restrict__ out)          // (B,1,T,F) complex pairs
{
    const unsigned bid = blockIdx.x;

    if (bid < FB) {
        // ---- deep-filter region: f in [0,96) ----
        const unsigned stride = FB * 256u;
        for (unsigned n = bid * 256u + threadIdx.x; n < (unsigned)N_FILT; n += stride) {
            const unsigned f  = n % (unsigned)NF;
            const unsigned bt = n / (unsigned)NF;       // b*T + t
            const unsigned t  = bt & (TT - 1u);
            const unsigned b  = bt >> 12;

            float accx = 0.f, accy = 0.f;
#pragma unroll
            for (int i = 0; i < FS; ++i) {
                const int ts = (int)t + i - (FS - 1);
                if (ts < 0) continue;
                const float2 s = spec[(b * TT + (unsigned)ts) * FF + f];
                const float2 c = coefs[((b * FS + (unsigned)i) * TT + t) * NF + f];
                accx = fmaf(s.x, c.x, accx);
                accx = fmaf(-s.y, c.y, accx);
                accy = fmaf(s.x, c.y, accy);
                accy = fmaf(s.y, c.x, accy);
            }
            float2 r; r.x = accx; r.y = accy;
            out[bt * FF + f] = r;
        }
    } else {
        // ---- passthrough region: f in [96,481) ----
        const unsigned stride = (NBLK - FB) * 256u;
        for (unsigned n = (bid - FB) * 256u + threadIdx.x; n < (unsigned)N_HI; n += stride) {
            const unsigned p  = n % (unsigned)(FF - NF);  // 0..384
            const unsigned bt = n / (unsigned)(FF - NF);  // b*T + t
            const unsigned idx = bt * FF + NF + p;
            out[idx] = spec[idx];
        }
    }
}

extern "C" void kernel_launch(void* const* d_in, const int* in_sizes, int n_in,
                              void* d_out, int out_size, void* d_ws, size_t ws_size,
                              hipStream_t stream) {
    const float2* spec  = (const float2*)d_in[0];
    const float2* coefs = (const float2*)d_in[1];
    float2* out = (float2*)d_out;

    df_all<<<dim3(NBLK), dim3(256), 0, stream>>>(spec, coefs, out);
}